// Round 1
// baseline (2105.378 us; speedup 1.0000x reference)
//
#include <hip/hip_runtime.h>

// Dims: x[b=32][i=2048][n=16], W[j=64][i=2048][m=32][n=16], bias[j][m], out v[b][j][m]
constexpr int B = 32, I = 2048, J = 64, M = 32, N = 16;
constexpr int IC = 16;          // i's per route block
constexpr int NIC = I / IC;     // 128 i-chunks
constexpr float FEPS = 1e-8f;

// Heavy pass: per (b-half, i-chunk) block, 1024 threads = 16 waves.
// wave = one b (16 b per block), lane = j (64 j = full wave -> softmax is wave-local).
// MODE 0: c = 1/64 exactly (softmax of zero logits), veff unused.
// MODE 1: logit = veff . u_hat, softmax over j.
// ATOMIC=false: write per-block partials P[bh][ic][wv][j][m]; ATOMIC=true: atomicAdd into s[b][j][m].
template<int MODE, bool ATOMIC>
__global__ __launch_bounds__(1024)
void route_pass(const float* __restrict__ W, const float* __restrict__ x,
                const float* __restrict__ veff, float* __restrict__ P)
{
    __shared__ float4 Wl[8192];                 // 128 KB: W[:, i, :, :] (XOR-swizzled)
    const int tid = threadIdx.x;
    const int j   = tid & 63;
    const int wv  = tid >> 6;                   // 0..15
    const int bh  = blockIdx.x & 1;
    const int ic  = blockIdx.x >> 1;            // 0..127  (bh-pair adjacent -> L2/L3 reuse of W slice)
    const int b   = bh * 16 + wv;
    const int swz = (j & 7) << 4;
    const int rowb = j << 11;                   // j * 2048 bytes (row base in LDS)

    float acc[M];
    #pragma unroll
    for (int m = 0; m < M; ++m) acc[m] = 0.f;

    for (int ii = 0; ii < IC; ++ii) {
        const int i = ic * IC + ii;
        __syncthreads();                        // previous iter's LDS reads done
        // ---- stage W[:, i, :, :]: 8192 float4, 8 per thread, coalesced ----
        #pragma unroll
        for (int k = 0; k < 8; ++k) {
            const int f   = k * 1024 + tid;     // float4 index: f = j*128 + m*4 + q
            const int jp  = f >> 7;
            const int rem = f & 127;
            const float4 w4 = *(const float4*)(W + (((size_t)jp << 20) + (size_t)i * 512 + (rem << 2)));
            *(float4*)((char*)Wl + ((f * 16) ^ ((jp & 7) << 4))) = w4;
        }
        // x row (wave-uniform address -> broadcast)
        const float* xr = x + (((size_t)b << 15) + (i << 4));
        const float4 xv0 = *(const float4*)(xr + 0);
        const float4 xv1 = *(const float4*)(xr + 4);
        const float4 xv2 = *(const float4*)(xr + 8);
        const float4 xv3 = *(const float4*)(xr + 12);
        __syncthreads();

        // ---- u_hat[m] = sum_n W[j,i,m,n] x[b,i,n]; logit = sum_m veff[b,j,m]*u_hat[m] ----
        float uh[M];
        float logit = 0.f;
        const char* wb = (const char*)Wl;
        #pragma unroll
        for (int mq = 0; mq < 8; ++mq) {
            float4 vvq = make_float4(0.f, 0.f, 0.f, 0.f);
            if (MODE != 0)
                vvq = *(const float4*)(veff + ((((size_t)b << 6) | j) << 5) + (mq << 2));
            #pragma unroll
            for (int mi = 0; mi < 4; ++mi) {
                const int m  = mq * 4 + mi;
                const int rb = rowb + (m << 6);
                const float4 w0 = *(const float4*)(wb + ((rb +  0) ^ swz));
                const float4 w1 = *(const float4*)(wb + ((rb + 16) ^ swz));
                const float4 w2 = *(const float4*)(wb + ((rb + 32) ^ swz));
                const float4 w3 = *(const float4*)(wb + ((rb + 48) ^ swz));
                float u = w0.x * xv0.x;
                u = fmaf(w0.y, xv0.y, u); u = fmaf(w0.z, xv0.z, u); u = fmaf(w0.w, xv0.w, u);
                u = fmaf(w1.x, xv1.x, u); u = fmaf(w1.y, xv1.y, u); u = fmaf(w1.z, xv1.z, u); u = fmaf(w1.w, xv1.w, u);
                u = fmaf(w2.x, xv2.x, u); u = fmaf(w2.y, xv2.y, u); u = fmaf(w2.z, xv2.z, u); u = fmaf(w2.w, xv2.w, u);
                u = fmaf(w3.x, xv3.x, u); u = fmaf(w3.y, xv3.y, u); u = fmaf(w3.z, xv3.z, u); u = fmaf(w3.w, xv3.w, u);
                uh[m] = u;
                const float vm = (mi == 0) ? vvq.x : (mi == 1) ? vvq.y : (mi == 2) ? vvq.z : vvq.w;
                logit = fmaf(u, vm, logit);
            }
        }
        // ---- softmax over j (full wave = 64 j for this b) ----
        float c;
        if (MODE == 0) {
            c = 1.0f / 64.0f;
        } else {
            float mx = logit;
            #pragma unroll
            for (int off = 32; off >= 1; off >>= 1) mx = fmaxf(mx, __shfl_xor(mx, off, 64));
            const float e = __expf(logit - mx);
            float sm = e;
            #pragma unroll
            for (int off = 32; off >= 1; off >>= 1) sm += __shfl_xor(sm, off, 64);
            c = e / sm;
        }
        #pragma unroll
        for (int m = 0; m < M; ++m) acc[m] = fmaf(c, uh[m], acc[m]);
    }

    if (ATOMIC) {
        float* s = P + ((((size_t)b << 6) | j) << 5);
        #pragma unroll
        for (int m = 0; m < M; ++m) atomicAdd(s + m, acc[m]);
    } else {
        float* pp = P + ((((size_t)bh * NIC + ic) * 16 + wv) * 2048) + (j << 5);
        #pragma unroll
        for (int mq = 0; mq < 8; ++mq)
            *(float4*)(pp + (mq << 2)) =
                make_float4(acc[mq*4], acc[mq*4+1], acc[mq*4+2], acc[mq*4+3]);
    }
}

// Reduce partials (128 slices), add bias, squash. 256 thr = 8 groups of 32 lanes (lane = m).
// If vold != null: write vold[idx] + v (running sum of v's for the logits-linearity trick).
template<bool ATOMIC>
__global__ __launch_bounds__(256)
void reduce_squash(const float* __restrict__ P, const float* __restrict__ bias,
                   float* __restrict__ vout, const float* __restrict__ vold)
{
    const int tid = threadIdx.x;
    const int m = tid & 31;
    const int g = tid >> 5;
    const int pair = blockIdx.x * 8 + g;        // 0..2047 = b*64 + j
    const int b = pair >> 6, j = pair & 63;
    float s;
    if (ATOMIC) {
        s = P[(((size_t)pair) << 5) + m];
    } else {
        const int bh = b >> 4, wv = b & 15;
        const float* base = P + (((size_t)bh * NIC * 16 + wv) * 2048) + (j << 5) + m;
        float s0 = 0.f, s1 = 0.f, s2 = 0.f, s3 = 0.f;
        #pragma unroll 4
        for (int q = 0; q < NIC / 4; ++q) {
            s0 += base[(size_t)(q * 4 + 0) * 32768];
            s1 += base[(size_t)(q * 4 + 1) * 32768];
            s2 += base[(size_t)(q * 4 + 2) * 32768];
            s3 += base[(size_t)(q * 4 + 3) * 32768];
        }
        s = (s0 + s1) + (s2 + s3);
    }
    s += bias[(j << 5) + m];
    float n2 = s * s;
    n2 += __shfl_xor(n2, 16, 64);
    n2 += __shfl_xor(n2,  8, 64);
    n2 += __shfl_xor(n2,  4, 64);
    n2 += __shfl_xor(n2,  2, 64);
    n2 += __shfl_xor(n2,  1, 64);
    float v = s * (n2 / (1.f + n2)) / sqrtf(n2 + FEPS);
    if (vold) v += vold[(((size_t)pair) << 5) + m];
    vout[(((size_t)pair) << 5) + m] = v;
}

extern "C" void kernel_launch(void* const* d_in, const int* in_sizes, int n_in,
                              void* d_out, int out_size, void* d_ws, size_t ws_size,
                              hipStream_t stream)
{
    const float* x    = (const float*)d_in[0];
    const float* W    = (const float*)d_in[1];
    const float* bias = (const float*)d_in[2];
    float* out = (float*)d_out;

    const size_t pFloats = (size_t)2 * NIC * 16 * 2048;     // 8,388,608 (32 MB)
    const size_t vFloats = (size_t)B * J * M;               // 65,536
    const bool bigws = ws_size >= (pFloats + 2 * vFloats) * sizeof(float);

    if (bigws) {
        float* P  = (float*)d_ws;
        float* v0 = P + pFloats;
        float* vs = v0 + vFloats;               // v0 + v1
        route_pass<0, false><<<256, 1024, 0, stream>>>(W, x, nullptr, P);
        reduce_squash<false><<<256, 256, 0, stream>>>(P, bias, v0, nullptr);
        route_pass<1, false><<<256, 1024, 0, stream>>>(W, x, v0, P);
        reduce_squash<false><<<256, 256, 0, stream>>>(P, bias, vs, v0);   // vs = v0 + v1
        route_pass<1, false><<<256, 1024, 0, stream>>>(W, x, vs, P);
        reduce_squash<false><<<256, 256, 0, stream>>>(P, bias, out, nullptr);
    } else {
        // small-ws fallback: atomic accumulation of s (needs 3*256 KB)
        float* s  = (float*)d_ws;
        float* v0 = s + vFloats;
        float* vs = v0 + vFloats;
        hipMemsetAsync(s, 0, vFloats * sizeof(float), stream);
        route_pass<0, true><<<256, 1024, 0, stream>>>(W, x, nullptr, s);
        reduce_squash<true><<<256, 256, 0, stream>>>(s, bias, v0, nullptr);
        hipMemsetAsync(s, 0, vFloats * sizeof(float), stream);
        route_pass<1, true><<<256, 1024, 0, stream>>>(W, x, v0, s);
        reduce_squash<true><<<256, 256, 0, stream>>>(s, bias, vs, v0);
        hipMemsetAsync(s, 0, vFloats * sizeof(float), stream);
        route_pass<1, true><<<256, 1024, 0, stream>>>(W, x, vs, s);
        reduce_squash<true><<<256, 256, 0, stream>>>(s, bias, out, nullptr);
    }
}

// Round 2
// 2089.236 us; speedup vs baseline: 1.0077x; 1.0077x over previous
//
#include <hip/hip_runtime.h>

// Dims: x[b=32][i=2048][n=16], W[j=64][i=2048][m=32][n=16], bias[j][m], out v[b][j][m]
constexpr int B = 32, I = 2048, J = 64, M = 32, N = 16;
constexpr int IC = 16;          // i's per route block
constexpr int NIC = I / IC;     // 128 i-chunks
constexpr float FEPS = 1e-8f;
constexpr int SLICE_FLOATS = B * J * M;   // 65536 floats = 256 KB per partial slice

// Heavy pass: per (b-half, i-chunk) block, 1024 threads = 16 waves.
// wave = one b (16 b per block), lane = j (64 j = full wave -> softmax is wave-local).
// MODE 0: c = 1/64 exactly (softmax of zero logits), veff unused.
// MODE 1: logit = veff . u_hat, softmax over j.
// STORE: unique slice per ic -> plain float4 stores (needs 128 slices = 32 MB ws).
// !STORE: atomicAdd into slice (ic % nslice) -- contention 128/nslice per address.
template<int MODE, bool STORE>
__global__ __launch_bounds__(1024)
void route_pass(const float* __restrict__ W, const float* __restrict__ x,
                const float* __restrict__ veff, float* __restrict__ P, int nslice)
{
    __shared__ float4 Wl[8192];                 // 128 KB: W[:, i, :, :] (XOR-swizzled)
    const int tid = threadIdx.x;
    const int j   = tid & 63;
    const int wv  = tid >> 6;                   // 0..15
    const int bh  = blockIdx.x & 1;
    const int ic  = blockIdx.x >> 1;            // 0..127  (bh-pair adjacent -> L3 dedup of W slice)
    const int b   = bh * 16 + wv;
    const int swz = (j & 7) << 4;
    const int rowb = j << 11;                   // j * 2048 bytes (row base in LDS)

    float acc[M];
    #pragma unroll
    for (int m = 0; m < M; ++m) acc[m] = 0.f;

    for (int ii = 0; ii < IC; ++ii) {
        const int i = ic * IC + ii;
        __syncthreads();                        // previous iter's LDS reads done
        // ---- stage W[:, i, :, :]: 8192 float4, 8 per thread, coalesced ----
        #pragma unroll
        for (int k = 0; k < 8; ++k) {
            const int f   = k * 1024 + tid;     // float4 index: f = jp*128 + rem
            const int jp  = f >> 7;
            const int rem = f & 127;
            const float4 w4 = *(const float4*)(W + (((size_t)jp << 20) + (size_t)i * 512 + (rem << 2)));
            *(float4*)((char*)Wl + ((f * 16) ^ ((jp & 7) << 4))) = w4;
        }
        // x row (wave-uniform address -> broadcast)
        const float* xr = x + (((size_t)b << 15) + (i << 4));
        const float4 xv0 = *(const float4*)(xr + 0);
        const float4 xv1 = *(const float4*)(xr + 4);
        const float4 xv2 = *(const float4*)(xr + 8);
        const float4 xv3 = *(const float4*)(xr + 12);
        __syncthreads();

        // ---- u_hat[m] = sum_n W[j,i,m,n] x[b,i,n]; logit = sum_m veff[b,j,m]*u_hat[m] ----
        float uh[M];
        float logit = 0.f;
        const char* wb = (const char*)Wl;
        #pragma unroll
        for (int mq = 0; mq < 8; ++mq) {
            float4 vvq = make_float4(0.f, 0.f, 0.f, 0.f);
            if (MODE != 0)
                vvq = *(const float4*)(veff + ((((size_t)b << 6) | j) << 5) + (mq << 2));
            #pragma unroll
            for (int mi = 0; mi < 4; ++mi) {
                const int m  = mq * 4 + mi;
                const int rb = rowb + (m << 6);
                const float4 w0 = *(const float4*)(wb + ((rb +  0) ^ swz));
                const float4 w1 = *(const float4*)(wb + ((rb + 16) ^ swz));
                const float4 w2 = *(const float4*)(wb + ((rb + 32) ^ swz));
                const float4 w3 = *(const float4*)(wb + ((rb + 48) ^ swz));
                float u = w0.x * xv0.x;
                u = fmaf(w0.y, xv0.y, u); u = fmaf(w0.z, xv0.z, u); u = fmaf(w0.w, xv0.w, u);
                u = fmaf(w1.x, xv1.x, u); u = fmaf(w1.y, xv1.y, u); u = fmaf(w1.z, xv1.z, u); u = fmaf(w1.w, xv1.w, u);
                u = fmaf(w2.x, xv2.x, u); u = fmaf(w2.y, xv2.y, u); u = fmaf(w2.z, xv2.z, u); u = fmaf(w2.w, xv2.w, u);
                u = fmaf(w3.x, xv3.x, u); u = fmaf(w3.y, xv3.y, u); u = fmaf(w3.z, xv3.z, u); u = fmaf(w3.w, xv3.w, u);
                uh[m] = u;
                const float vm = (mi == 0) ? vvq.x : (mi == 1) ? vvq.y : (mi == 2) ? vvq.z : vvq.w;
                logit = fmaf(u, vm, logit);
            }
        }
        // ---- softmax over j (full wave = 64 j for this b) ----
        float c;
        if (MODE == 0) {
            c = 1.0f / 64.0f;
        } else {
            float mx = logit;
            #pragma unroll
            for (int off = 32; off >= 1; off >>= 1) mx = fmaxf(mx, __shfl_xor(mx, off, 64));
            const float e = __expf(logit - mx);
            float sm = e;
            #pragma unroll
            for (int off = 32; off >= 1; off >>= 1) sm += __shfl_xor(sm, off, 64);
            c = e / sm;
        }
        #pragma unroll
        for (int m = 0; m < M; ++m) acc[m] = fmaf(c, uh[m], acc[m]);
    }

    // ---- write partials: P[slice][b][j][m] ----
    if (STORE) {
        float* pp = P + ((size_t)ic * SLICE_FLOATS) + (((b << 6) | j) << 5);
        #pragma unroll
        for (int mq = 0; mq < 8; ++mq)
            *(float4*)(pp + (mq << 2)) =
                make_float4(acc[mq*4], acc[mq*4+1], acc[mq*4+2], acc[mq*4+3]);
    } else {
        const int slice = ic % nslice;
        float* pp = P + ((size_t)slice * SLICE_FLOATS) + (((b << 6) | j) << 5);
        #pragma unroll
        for (int m = 0; m < M; ++m) atomicAdd(pp + m, acc[m]);
    }
}

// Reduce nsum slices, add bias, squash. 256 thr = 8 groups of 32 lanes (lane = m).
// If vold != null: vout[idx] = vold[idx] + v (running sum for logits-linearity). vold may alias vout.
__global__ __launch_bounds__(256)
void reduce_squash(const float* __restrict__ P, const float* __restrict__ bias,
                   float* __restrict__ vout, const float* __restrict__ vold, int nsum)
{
    const int tid = threadIdx.x;
    const int m = tid & 31;
    const int g = tid >> 5;
    const int pair = blockIdx.x * 8 + g;        // 0..2047 = b*64 + j
    const int j = pair & 63;
    const float* base = P + (((size_t)pair) << 5) + m;
    float s0 = 0.f, s1 = 0.f, s2 = 0.f, s3 = 0.f;
    int q = 0;
    for (; q + 4 <= nsum; q += 4) {
        s0 += base[(size_t)(q + 0) * SLICE_FLOATS];
        s1 += base[(size_t)(q + 1) * SLICE_FLOATS];
        s2 += base[(size_t)(q + 2) * SLICE_FLOATS];
        s3 += base[(size_t)(q + 3) * SLICE_FLOATS];
    }
    for (; q < nsum; ++q) s0 += base[(size_t)q * SLICE_FLOATS];
    float s = (s0 + s1) + (s2 + s3);
    s += bias[(j << 5) + m];
    float n2 = s * s;
    n2 += __shfl_xor(n2, 16, 64);
    n2 += __shfl_xor(n2,  8, 64);
    n2 += __shfl_xor(n2,  4, 64);
    n2 += __shfl_xor(n2,  2, 64);
    n2 += __shfl_xor(n2,  1, 64);
    float v = s * (n2 / (1.f + n2)) / sqrtf(n2 + FEPS);
    if (vold) v += vold[(((size_t)pair) << 5) + m];
    vout[(((size_t)pair) << 5) + m] = v;
}

extern "C" void kernel_launch(void* const* d_in, const int* in_sizes, int n_in,
                              void* d_out, int out_size, void* d_ws, size_t ws_size,
                              hipStream_t stream)
{
    const float* x    = (const float*)d_in[0];
    const float* W    = (const float*)d_in[1];
    const float* bias = (const float*)d_in[2];
    float* out = (float*)d_out;

    // Partial slices live in ws; running-v lives in d_out (overwritten by final pass).
    float* P = (float*)d_ws;
    float* vrun = out;

    const size_t wsFloats = ws_size / sizeof(float);
    int nslice = (int)(wsFloats / SLICE_FLOATS);
    if (nslice < 1) nslice = 1;                 // ws >= 768 KB observed; degenerate guard
    if (nslice > NIC) nslice = NIC;
    const bool store = (nslice == NIC);         // 128 slices = 32 MB: exclusive writers
    const int nsum = store ? NIC : nslice;
    const size_t pBytes = (size_t)nsum * SLICE_FLOATS * sizeof(float);

    if (store) {
        route_pass<0, true><<<256, 1024, 0, stream>>>(W, x, nullptr, P, nslice);
        reduce_squash<<<256, 256, 0, stream>>>(P, bias, vrun, nullptr, nsum);   // vrun = v0
        route_pass<1, true><<<256, 1024, 0, stream>>>(W, x, vrun, P, nslice);
        reduce_squash<<<256, 256, 0, stream>>>(P, bias, vrun, vrun, nsum);      // vrun = v0 + v1
        route_pass<1, true><<<256, 1024, 0, stream>>>(W, x, vrun, P, nslice);
        reduce_squash<<<256, 256, 0, stream>>>(P, bias, out, nullptr, nsum);    // final v
    } else {
        hipMemsetAsync(P, 0, pBytes, stream);
        route_pass<0, false><<<256, 1024, 0, stream>>>(W, x, nullptr, P, nslice);
        reduce_squash<<<256, 256, 0, stream>>>(P, bias, vrun, nullptr, nsum);
        hipMemsetAsync(P, 0, pBytes, stream);
        route_pass<1, false><<<256, 1024, 0, stream>>>(W, x, vrun, P, nslice);
        reduce_squash<<<256, 256, 0, stream>>>(P, bias, vrun, vrun, nsum);
        hipMemsetAsync(P, 0, pBytes, stream);
        route_pass<1, false><<<256, 1024, 0, stream>>>(W, x, vrun, P, nslice);
        reduce_squash<<<256, 256, 0, stream>>>(P, bias, out, nullptr, nsum);
    }
}